// Round 1
// baseline (431.637 us; speedup 1.0000x reference)
//
#include <hip/hip_runtime.h>

// Correlation volume, N=8, Z=128, H=W=160, 81 integer shifts (9 dy x 9 dx).
// Structure: NO LDS, NO barriers. Each wave independently owns one
// (16x32 output tile, dy) pair and streams z=0..127, loading a[8]+b[16]
// per z directly from global (L1/L2-cached across the 9 dy-waves that share
// a tile). Blocks = 3 waves (dy triple of one tile) -> 1200 blocks.
// XCD swizzle: bid%8 selects the image, so each XCD's L2 holds exactly one
// image's A/B (essential: without it each tile's dy-blocks land on all 8
// XCDs and A/B are HBM-fetched ~8x).
#define NB 8
#define ZD 128
#define HD 160
#define WD 160
#define PLANE (HD * WD)            // 25600
#define IMG (ZD * PLANE)

#define TI 16
#define TJ 32
#define TILES_PER_IMG 50           // 10 (rows) x 5 (cols)
#define DQ 3                       // dy-groups per tile -> 3 waves/block
#define NTHREADS 192

// Issue 6 loads (a: 2x float4, b: 4x float4) for the current z, then advance.
// Invalid (OOB) b-segments point at the zero page with stride 0.
#define LOADS(aa, bb) do { \
    *(float4*)(&aa[0])  = *(const float4*)(pa); \
    *(float4*)(&aa[4])  = *(const float4*)(pa + 4); \
    *(float4*)(&bb[0])  = *(const float4*)(pb0); \
    *(float4*)(&bb[4])  = *(const float4*)(pb1); \
    *(float4*)(&bb[8])  = *(const float4*)(pb2); \
    *(float4*)(&bb[12]) = *(const float4*)(pb3); \
    pa += PLANE; pb0 += s0; pb1 += s1; pb2 += s2; pb3 += s3; \
} while (0)

#define FMAS(aa, bb) do { \
    _Pragma("unroll") \
    for (int d = 0; d < 9; ++d) { \
        _Pragma("unroll") \
        for (int p = 0; p < 8; ++p) \
            acc[d][p] = fmaf(aa[p], bb[p + d], acc[d][p]); \
    } \
} while (0)

__global__ __launch_bounds__(NTHREADS, 3)
void corr_vol_kernel(const float* __restrict__ A, const float* __restrict__ B,
                     const float* __restrict__ zp, float* __restrict__ out) {
    const int bid = blockIdx.x;
    const int x  = bid & 7;            // XCD (dispatch round-robins bid%8)
    const int s  = bid >> 3;           // 0..149 within XCD
    const int tl = s / DQ;             // local tile 0..49
    const int dq = s - DQ * tl;        // dy-triple 0..2
    const int tile = x * TILES_PER_IMG + tl;
    const int n  = tile / TILES_PER_IMG;       // == x
    const int t2 = tile - n * TILES_PER_IMG;
    const int it = t2 / 5, jt = t2 - 5 * it;
    const int i0 = it * TI, j0 = jt * TJ;

    const int w = dq * 3 + (threadIdx.x >> 6); // dy index 0..8 (this wave's)
    const int l = threadIdx.x & 63;
    const int r = l >> 2;              // pixel row 0..15
    const int g = l & 3;               // col group (8 cols each)

    // A pointer: always in-bounds (tile interior).
    const float* pa = A + (size_t)n * IMG + (size_t)(i0 + r) * WD + (j0 + 8 * g);

    // B descriptors: 4 float4 segments covering cols [j0+8g-4, j0+8g+11],
    // row i0+r+w-4. OOB segment -> zero page, stride 0.
    const int br = i0 + r + w - 4;
    const bool rv = (unsigned)br < (unsigned)HD;
    const float* bbase = B + (size_t)n * IMG + (size_t)br * WD + (j0 + 8 * g - 4);
    const int c0 = j0 + 8 * g - 4;     // col of segment 0 (multiple of 4)

    const float *pb0, *pb1, *pb2, *pb3;
    int s0, s1, s2, s3;
    {
        bool v;
        v = rv && ((unsigned)(c0 +  0) < (unsigned)WD);
        pb0 = v ? bbase +  0 : zp;  s0 = v ? PLANE : 0;
        v = rv && ((unsigned)(c0 +  4) < (unsigned)WD);
        pb1 = v ? bbase +  4 : zp;  s1 = v ? PLANE : 0;
        v = rv && ((unsigned)(c0 +  8) < (unsigned)WD);
        pb2 = v ? bbase +  8 : zp;  s2 = v ? PLANE : 0;
        v = rv && ((unsigned)(c0 + 12) < (unsigned)WD);
        pb3 = v ? bbase + 12 : zp;  s3 = v ? PLANE : 0;
    }

    float acc[9][8];
    #pragma unroll
    for (int d = 0; d < 9; ++d)
        #pragma unroll
        for (int p = 0; p < 8; ++p) acc[d][p] = 0.f;

    // Register double-buffer: (a0,b0) holds z, (a1,b1) holds z+1.
    float a0[8], b0[16], a1[8], b1[16];
    LOADS(a0, b0);                     // z = 0
    LOADS(a1, b1);                     // z = 1

    #pragma unroll 1
    for (int z = 0; z < ZD - 2; z += 2) {
        FMAS(a0, b0);                  // consume z
        LOADS(a0, b0);                 // issue z+2
        FMAS(a1, b1);                  // consume z+1
        LOADS(a1, b1);                 // issue z+3
    }
    FMAS(a0, b0);                      // z = 126
    FMAS(a1, b1);                      // z = 127

    // Epilogue: out[k = d*9 + w]; lanes of a wave cover 16 rows x 32 cols.
    float* obase = out + (((size_t)n * 81) * HD + (i0 + r)) * WD + j0 + 8 * g;
    #pragma unroll
    for (int d = 0; d < 9; ++d) {
        const int kk = d * 9 + w;
        float* o = obase + (size_t)kk * PLANE;
        *(float4*)(&o[0]) = make_float4(acc[d][0], acc[d][1], acc[d][2], acc[d][3]);
        *(float4*)(&o[4]) = make_float4(acc[d][4], acc[d][5], acc[d][6], acc[d][7]);
    }
}

extern "C" void kernel_launch(void* const* d_in, const int* in_sizes, int n_in,
                              void* d_out, int out_size, void* d_ws, size_t ws_size,
                              hipStream_t stream) {
    const float* A = (const float*)d_in[0];
    const float* B = (const float*)d_in[1];
    float* out = (float*)d_out;
    // 256 B zero page for OOB b-segments (d_ws is re-poisoned every launch).
    hipMemsetAsync(d_ws, 0, 256, stream);
    corr_vol_kernel<<<dim3(NB * TILES_PER_IMG * DQ), dim3(NTHREADS), 0, stream>>>(
        A, B, (const float*)d_ws, out);
}